// Round 7
// baseline (532.689 us; speedup 1.0000x reference)
//
#include <hip/hip_runtime.h>

// ---- filter / neuron constants (double, matching the Python reference) ----
#define EMD 0.8824969025845955      // exp(-1/8)
#define ESD 0.6065306597126334      // exp(-1/2)
#define A1C ((float)(EMD + ESD))                    // y[t-1] coeff
#define A2C ((float)(-(EMD * ESD)))                 // y[t-2] coeff
#define BC  ((float)((8.0 / 6.0) * (EMD - ESD)))    // x[t] coeff (ETA=8/6)
#define EMF ((float)EMD)                            // reset decay

// B=64, T=300. Layers: 300 -> 500 -> 200 -> 500 -> 300.
//
// Exactness contract (absmax 0.0, rounds 1-6): reference currents are a
// SEQUENTIAL ascending-i fp32 fold of W[o,i]*s[i]; spikes are exactly 0/1.
// Skipping s==0 terms is bitwise-neutral; processing set bits in ascending
// order per t-row is the SAME add sequence. Interleaving TWO t-rows is exact
// too: they accumulate into different registers.

// ---------------------------------------------------------------------------
// Generic batched transpose: src [Bt][R][C] -> dst [Bt][C][R]
// ---------------------------------------------------------------------------
__global__ __launch_bounds__(256) void transpose_rc(
    const float* __restrict__ src, float* __restrict__ dst, int R, int C)
{
    __shared__ float tile[32][33];
    const int c0 = blockIdx.x * 32;
    const int r0 = blockIdx.y * 32;
    const int b  = blockIdx.z;
    const float* S = src + (size_t)b * R * C;
    float* D = dst + (size_t)b * R * C;
    const int tx = threadIdx.x;      // 0..31
    const int ty = threadIdx.y;      // 0..7
#pragma unroll
    for (int s = 0; s < 4; s++) {
        const int r = r0 + ty + 8 * s;
        const int c = c0 + tx;
        if (r < R && c < C) tile[ty + 8 * s][tx] = S[(size_t)r * C + c];
    }
    __syncthreads();
#pragma unroll
    for (int s = 0; s < 4; s++) {
        const int c = c0 + ty + 8 * s;
        const int r = r0 + tx;
        if (c < C && r < R) D[(size_t)c * R + r] = tile[tx][ty + 8 * s];
    }
}

// ---------------------------------------------------------------------------
// Sparse spike GEMM: C[b,t,o] = sum_i Wt[i,o] * S[b,t,i], skipping S==0.
// S: [B,T,K] binary, Wt: [K,O], C: [B,T,O].
// Block: 256 thr (4 waves), o-chunk 128 (2 o's/lane), t-chunk 32 (8 t/wave),
// K staged in 64-row LDS chunks (32 KB), register-prefetched one chunk ahead.
// Inner loop: PAIRS of t-rows interleaved, 4 bits each -> 8 independent
// ds_read_b64 in flight (round-6 had 4; VALUBusy 25% = latency-exposed).
// ---------------------------------------------------------------------------
#define KG  64
#define OCN 128
#define TCN 32

__global__ __launch_bounds__(256) void spmm_snn(
    const float* __restrict__ S, const float* __restrict__ Wt,
    float* __restrict__ C, int K, int O, int T)
{
    __shared__ float Wls[KG * OCN];   // 32 KB
    const int tid  = threadIdx.x;
    const int lane = tid & 63;
    const int wv   = tid >> 6;        // 0..3
    const int oc   = blockIdx.x * OCN;
    const int t0   = blockIdx.y * TCN;
    const int b    = blockIdx.z;

    const float* Sb = S + (size_t)b * T * K;
    float* Cb = C + (size_t)b * T * O;

    // staging decomposition: idx -> (row 0..63, col4 0..124)
    const int srow  = tid >> 5;        // base row (stride 8 over r)
    const int scol4 = (tid & 31) * 4;

    float2 acc[8];
#pragma unroll
    for (int u = 0; u < 8; u++) acc[u] = make_float2(0.f, 0.f);

    const int nkc = (K + KG - 1) / KG;
    float4 wpf[8];

#define LOADW(kc)                                                              \
    {                                                                          \
        const int kb_ = (kc) * KG;                                             \
        _Pragma("unroll")                                                      \
        for (int r = 0; r < 8; r++) {                                          \
            const int k = kb_ + srow + r * 8;                                  \
            const int o = oc + scol4;                                          \
            float4 w = make_float4(0.f, 0.f, 0.f, 0.f);                        \
            if (k < K && o + 3 < O)                                            \
                w = *reinterpret_cast<const float4*>(&Wt[(size_t)k * O + o]);  \
            wpf[r] = w;                                                        \
        }                                                                      \
    }

#define STOREW()                                                               \
    {                                                                          \
        _Pragma("unroll")                                                      \
        for (int r = 0; r < 8; r++)                                            \
            *reinterpret_cast<float4*>(&Wls[(srow + r * 8) * OCN + scol4]) = wpf[r]; \
    }

// pop 4 ascending bits of `m` into j0..j3 (wave-uniform SALU chain)
#define POP4(m, j0, j1, j2, j3)                                                \
    const int j0 = __builtin_ctzll(m); m &= m - 1;                             \
    const int j1 = __builtin_ctzll(m); m &= m - 1;                             \
    const int j2 = __builtin_ctzll(m); m &= m - 1;                             \
    const int j3 = __builtin_ctzll(m); m &= m - 1;

    LOADW(0)
    STOREW()
    __syncthreads();

    const float* wlane = &Wls[lane * 2];   // row j lives at offset j*OCN

    for (int kc = 0; kc < nkc; kc++) {
        const int kbase = kc * KG;
        if (kc + 1 < nkc) LOADW(kc + 1)    // overlaps the bit loops below

        // batch the spike loads (independent), then ballot per t
        float sv[8];
        const int k = kbase + lane;
#pragma unroll
        for (int u = 0; u < 8; u++) {
            const int t = t0 + u * 4 + wv;            // wave-uniform
            sv[u] = (t < T && k < K) ? Sb[(size_t)t * K + k] : 0.0f;
        }
#pragma unroll
        for (int up = 0; up < 4; up++) {
            const int u0 = up * 2, u1 = up * 2 + 1;
            unsigned long long m0 = __ballot(sv[u0] != 0.0f);
            unsigned long long m1 = __ballot(sv[u1] != 0.0f);
            int n0 = __popcll(m0), n1 = __popcll(m1);
            float ax0 = acc[u0].x, ay0 = acc[u0].y;
            float ax1 = acc[u1].x, ay1 = acc[u1].y;
            // joint phase: 8 independent LDS reads in flight
            while (n0 >= 4 && n1 >= 4) {
                POP4(m0, a0, a1, a2, a3)
                POP4(m1, b0, b1, b2, b3)
                const float2 wa0 = *reinterpret_cast<const float2*>(&wlane[a0 * OCN]);
                const float2 wa1 = *reinterpret_cast<const float2*>(&wlane[a1 * OCN]);
                const float2 wa2 = *reinterpret_cast<const float2*>(&wlane[a2 * OCN]);
                const float2 wa3 = *reinterpret_cast<const float2*>(&wlane[a3 * OCN]);
                const float2 wb0 = *reinterpret_cast<const float2*>(&wlane[b0 * OCN]);
                const float2 wb1 = *reinterpret_cast<const float2*>(&wlane[b1 * OCN]);
                const float2 wb2 = *reinterpret_cast<const float2*>(&wlane[b2 * OCN]);
                const float2 wb3 = *reinterpret_cast<const float2*>(&wlane[b3 * OCN]);
                ax0 += wa0.x; ay0 += wa0.y; ax0 += wa1.x; ay0 += wa1.y;
                ax0 += wa2.x; ay0 += wa2.y; ax0 += wa3.x; ay0 += wa3.y;
                ax1 += wb0.x; ay1 += wb0.y; ax1 += wb1.x; ay1 += wb1.y;
                ax1 += wb2.x; ay1 += wb2.y; ax1 += wb3.x; ay1 += wb3.y;
                n0 -= 4; n1 -= 4;
            }
            // drain row 0
            while (n0 >= 4) {
                POP4(m0, a0, a1, a2, a3)
                const float2 w0 = *reinterpret_cast<const float2*>(&wlane[a0 * OCN]);
                const float2 w1 = *reinterpret_cast<const float2*>(&wlane[a1 * OCN]);
                const float2 w2 = *reinterpret_cast<const float2*>(&wlane[a2 * OCN]);
                const float2 w3 = *reinterpret_cast<const float2*>(&wlane[a3 * OCN]);
                ax0 += w0.x; ay0 += w0.y; ax0 += w1.x; ay0 += w1.y;
                ax0 += w2.x; ay0 += w2.y; ax0 += w3.x; ay0 += w3.y;
                n0 -= 4;
            }
            while (n0 > 0) {
                const int j = __builtin_ctzll(m0); m0 &= m0 - 1;
                const float2 w = *reinterpret_cast<const float2*>(&wlane[j * OCN]);
                ax0 += w.x; ay0 += w.y;
                n0--;
            }
            // drain row 1
            while (n1 >= 4) {
                POP4(m1, b0, b1, b2, b3)
                const float2 w0 = *reinterpret_cast<const float2*>(&wlane[b0 * OCN]);
                const float2 w1 = *reinterpret_cast<const float2*>(&wlane[b1 * OCN]);
                const float2 w2 = *reinterpret_cast<const float2*>(&wlane[b2 * OCN]);
                const float2 w3 = *reinterpret_cast<const float2*>(&wlane[b3 * OCN]);
                ax1 += w0.x; ay1 += w0.y; ax1 += w1.x; ay1 += w1.y;
                ax1 += w2.x; ay1 += w2.y; ax1 += w3.x; ay1 += w3.y;
                n1 -= 4;
            }
            while (n1 > 0) {
                const int j = __builtin_ctzll(m1); m1 &= m1 - 1;
                const float2 w = *reinterpret_cast<const float2*>(&wlane[j * OCN]);
                ax1 += w.x; ay1 += w.y;
                n1--;
            }
            acc[u0].x = ax0; acc[u0].y = ay0;
            acc[u1].x = ax1; acc[u1].y = ay1;
        }
        if (kc + 1 < nkc) {
            __syncthreads();
            STOREW()
            __syncthreads();
        }
    }
#pragma unroll
    for (int u = 0; u < 8; u++) {
        const int t = t0 + u * 4 + wv;
        const int o = oc + lane * 2;
        if (t < T && o + 1 < O)               // O even -> pair all-or-nothing
            *reinterpret_cast<float2*>(&Cb[(size_t)t * O + o]) = acc[u];
    }
}

// ---------------------------------------------------------------------------
// LIF in time-major layout, in-place: C[b,t,o] currents -> spikes.
// One thread per (b,o); strided (stride O) column walk with 8-deep unrolled
// prefetch ring (constant indices -> stays in VGPRs). T fixed at 300.
// ---------------------------------------------------------------------------
#define LIF_STEP_S(xval, sval)                                                 \
    {                                                                          \
        const float y = A1 * y1 + A2 * y2 + Bc * (xval); y2 = y1; y1 = y;      \
        const float v = y + bi + r;                                            \
        sval = (v >= 1.0f) ? 1.0f : 0.0f;                                      \
        r = r * EMF - sval;                                                    \
    }

__global__ __launch_bounds__(64) void lif_t(
    float* __restrict__ C, const float* __restrict__ bias,
    const float* __restrict__ a1p, const float* __restrict__ a2p,
    const float* __restrict__ bp, int O)
{
    const int o = blockIdx.x * 64 + threadIdx.x;
    const int b = blockIdx.y;
    if (o >= O) return;
    const float A1 = a1p[0], A2 = a2p[0], Bc = bp[0];
    const float bi = bias[o];
    float* col = C + (size_t)b * 300 * O + o;

    float pf[8];
#pragma unroll
    for (int u = 0; u < 8; u++) pf[u] = col[(size_t)u * O];

    float y1 = 0.f, y2 = 0.f, r = 0.f;
    for (int blk = 0; blk < 37; blk++) {       // t = 0..295
#pragma unroll
        for (int u = 0; u < 8; u++) {
            const int t = blk * 8 + u;
            const float x = pf[u];
            if (t + 8 < 300) pf[u] = col[(size_t)(t + 8) * O];
            float s;
            LIF_STEP_S(x, s)
            col[(size_t)t * O] = s;
        }
    }
#pragma unroll
    for (int u = 0; u < 4; u++) {              // t = 296..299
        const float x = pf[u];
        float s;
        LIF_STEP_S(x, s)
        col[(size_t)(296 + u) * O] = s;
    }
}

// ---------------------------------------------------------------------------
// Layer-4 LIF + fixed output dual-exp IIR. C: currents->spikes (in place),
// F: filtered output. Both [B,T,O], O=300.
// ---------------------------------------------------------------------------
__global__ __launch_bounds__(64) void lif4_t(
    float* __restrict__ C, float* __restrict__ F,
    const float* __restrict__ bias,
    const float* __restrict__ a1p, const float* __restrict__ a2p,
    const float* __restrict__ bp, int O)
{
    const int o = blockIdx.x * 64 + threadIdx.x;
    const int b = blockIdx.y;
    if (o >= O) return;
    const float A1 = a1p[0], A2 = a2p[0], Bc = bp[0];
    const float bi = bias[o];
    float* col  = C + (size_t)b * 300 * O + o;
    float* fcol = F + (size_t)b * 300 * O + o;

    float pf[8];
#pragma unroll
    for (int u = 0; u < 8; u++) pf[u] = col[(size_t)u * O];

    float y1 = 0.f, y2 = 0.f, r = 0.f;
    float z1 = 0.f, z2 = 0.f;
    for (int blk = 0; blk < 37; blk++) {
#pragma unroll
        for (int u = 0; u < 8; u++) {
            const int t = blk * 8 + u;
            const float x = pf[u];
            if (t + 8 < 300) pf[u] = col[(size_t)(t + 8) * O];
            float s;
            LIF_STEP_S(x, s)
            const float z = A1C * z1 + A2C * z2 + BC * s; z2 = z1; z1 = z;
            col[(size_t)t * O]  = s;
            fcol[(size_t)t * O] = z;
        }
    }
#pragma unroll
    for (int u = 0; u < 4; u++) {
        const int t = 296 + u;
        const float x = pf[u];
        float s;
        LIF_STEP_S(x, s)
        const float z = A1C * z1 + A2C * z2 + BC * s; z2 = z1; z1 = z;
        col[(size_t)t * O]  = s;
        fcol[(size_t)t * O] = z;
    }
}

// ---------------------------------------------------------------------------
extern "C" void kernel_launch(void* const* d_in, const int* in_sizes, int n_in,
                              void* d_out, int out_size, void* d_ws, size_t ws_size,
                              hipStream_t stream)
{
    const float* inputs = (const float*)d_in[0];           // [64,300,300] binary
    const float* a1_1 = (const float*)d_in[1];
    const float* a2_1 = (const float*)d_in[2];
    const float* b_1  = (const float*)d_in[3];
    const float* W1   = (const float*)d_in[4];             // [500,300]
    const float* bias1= (const float*)d_in[5];
    const float* a1_2 = (const float*)d_in[6];
    const float* a2_2 = (const float*)d_in[7];
    const float* b_2  = (const float*)d_in[8];
    const float* W2   = (const float*)d_in[9];             // [200,500]
    const float* bias2= (const float*)d_in[10];
    const float* a1_3 = (const float*)d_in[11];
    const float* a2_3 = (const float*)d_in[12];
    const float* b_3  = (const float*)d_in[13];
    const float* W3   = (const float*)d_in[14];            // [500,200]
    const float* bias3= (const float*)d_in[15];
    const float* a1_4 = (const float*)d_in[16];
    const float* a2_4 = (const float*)d_in[17];
    const float* b_4  = (const float*)d_in[18];
    const float* W4   = (const float*)d_in[19];            // [300,500]
    const float* bias4= (const float*)d_in[20];

    const int B = 64, T = 300;

    // Workspace (proven size 53.76 MB): c1 = 9.6M floats, c2 = 3.84M floats.
    float* ws = (float*)d_ws;
    float* c1 = ws;                 // [B,T,500]; later filt_tmp [B,T,300]
    float* c2 = ws + 9600000;       // [B,T,200]

    // d_out regions double as scratch until the final transposes:
    // region1 [0..5.76M): Wt1..4 (500K floats), later final s4 [B,O,T]
    // region2 [5.76M..11.52M): inputT/c4/s4_tmp [B,T,300], later final filt
    float* out = (float*)d_out;
    float* reg1 = out;
    float* reg2 = out + 5760000;
    float* Wt1 = reg1;              // [300,500] = 150000
    float* Wt2 = reg1 + 150000;     // [500,200] = 100000
    float* Wt3 = reg1 + 250000;     // [200,500] = 100000
    float* Wt4 = reg1 + 350000;     // [500,300] = 150000

    const dim3 tb(32, 8);

    // Weight transposes W[O,K] -> Wt[K,O]
    transpose_rc<<<dim3(10, 16, 1), tb, 0, stream>>>(W1, Wt1, 500, 300);
    transpose_rc<<<dim3(16,  7, 1), tb, 0, stream>>>(W2, Wt2, 200, 500);
    transpose_rc<<<dim3( 7, 16, 1), tb, 0, stream>>>(W3, Wt3, 500, 200);
    transpose_rc<<<dim3(16, 10, 1), tb, 0, stream>>>(W4, Wt4, 300, 500);
    // Input spikes [B,IN,T] -> [B,T,IN]
    transpose_rc<<<dim3(10, 10, B), tb, 0, stream>>>(inputs, reg2, 300, 300);

    // Layer 1: 300 -> 500
    spmm_snn<<<dim3(4, 10, B), 256, 0, stream>>>(reg2, Wt1, c1, 300, 500, T);
    lif_t<<<dim3(8, B), 64, 0, stream>>>(c1, bias1, a1_1, a2_1, b_1, 500);
    // Layer 2: 500 -> 200
    spmm_snn<<<dim3(2, 10, B), 256, 0, stream>>>(c1, Wt2, c2, 500, 200, T);
    lif_t<<<dim3(4, B), 64, 0, stream>>>(c2, bias2, a1_2, a2_2, b_2, 200);
    // Layer 3: 200 -> 500 (write into c1; s1 dead)
    spmm_snn<<<dim3(4, 10, B), 256, 0, stream>>>(c2, Wt3, c1, 200, 500, T);
    lif_t<<<dim3(8, B), 64, 0, stream>>>(c1, bias3, a1_3, a2_3, b_3, 500);
    // Layer 4: 500 -> 300 into reg2 (inputT dead); LIF+filter, filt_tmp -> c1
    spmm_snn<<<dim3(3, 10, B), 256, 0, stream>>>(c1, Wt4, reg2, 500, 300, T);
    lif4_t<<<dim3(5, B), 64, 0, stream>>>(reg2, c1, bias4, a1_4, a2_4, b_4, 300);

    // Final transposes [B,T,O] -> [B,O,T]: s4 first (frees reg2), then filt.
    transpose_rc<<<dim3(10, 10, B), tb, 0, stream>>>(reg2, reg1, 300, 300);
    transpose_rc<<<dim3(10, 10, B), tb, 0, stream>>>(c1, reg2, 300, 300);
}